// Round 6
// baseline (233.849 us; speedup 1.0000x reference)
//
#include <hip/hip_runtime.h>
#include <math.h>

// B=16, C=512, HW=1024.  Chain (per batch):
//   X  (C x HW)  = n1 @ W_c^T
//   E  (HW x HW) = X^T @ n2
//   A  = row-softmax(E)
//   out(C x HW)  = n2 @ A
//
// Round 13 = round 12 + numerical-consistency fix:
//  - gemm2's fused softmax stats are now computed from the f16-ROUNDED acc
//    values ((float)(f16)acc), matching exactly what gemm3 reads back from
//    Et. Round 12 used raw f32 acc -> numerator (f16) / denominator (f32)
//    mismatch -> absmax 0.219 > 0.2125. Rounding first restores the f16
//    error cancellation (rounds 8-11: absmax 0.078).
//  - Everything else unchanged: 128x128 tiles, 256 threads, 4 waves 64x64,
//    both-sides XOR swizzle, depth-2 reg prefetch, exp fused in gemm3
//    B-staging, stats_partial pass deleted.
//
// Workspace (96 MiB, lifetime-aliased):
//   [0,16M):   n2t  f16 (prep -> gemm2)
//   [16,32M):  Xt   f16 (gemm1 -> gemm2)
//   [32,34M):  Wf   f16 (prep -> gemm1; overlaid by Et)
//   [32,64M):  Et   f16 (gemm2 -> gemm3)
//   [64,80M):  n1f  f16 (prep -> gemm1); Pm/Ps/Sc overlay afterwards
//   [80,96M):  n2f  f16 (prep -> gemm3)

typedef _Float16 f16;
typedef _Float16 f16x8 __attribute__((ext_vector_type(8)));
typedef _Float16 f16x4 __attribute__((ext_vector_type(4)));
typedef float f32x4 __attribute__((ext_vector_type(4)));

#define L2E 1.442695040888963f

// Barrier with LDS-drain only (no vmcnt drain): prefetch survives it.
#define WG_BARRIER() asm volatile("s_waitcnt lgkmcnt(0)\ns_barrier" ::: "memory")

// ---------------------------------------------------------------------------
// Fused pre-pass. blockIdx.x:
//   [0,4096):    n1 -> n1f     [4096,4608): Wc -> Wf
//   [4608,6656): n2 -> n2f (natural) + n2t (transposed)
__global__ __launch_bounds__(256) void prep(const float* __restrict__ n1,
                                            const float* __restrict__ Wc,
                                            const float* __restrict__ n2,
                                            f16* __restrict__ n1f, f16* __restrict__ Wf,
                                            f16* __restrict__ n2f, f16* __restrict__ n2t) {
    const int bid = blockIdx.x, tid = threadIdx.x;
    if (bid < 4608) {
        const float* s = (bid < 4096) ? n1 : Wc;
        f16* d = (bid < 4096) ? n1f : Wf;
        const size_t i = ((size_t)(bid < 4096 ? bid : bid - 4096) * 256 + tid) * 8;
        f32x4 a = *(const f32x4*)(s + i);
        f32x4 b = *(const f32x4*)(s + i + 4);
        f16x8 o;
        o[0] = (f16)a[0]; o[1] = (f16)a[1]; o[2] = (f16)a[2]; o[3] = (f16)a[3];
        o[4] = (f16)b[0]; o[5] = (f16)b[1]; o[6] = (f16)b[2]; o[7] = (f16)b[3];
        *(f16x8*)(d + i) = o;
        return;
    }
    const int id = bid - 4608;
    const int b = id >> 7;
    const int ry = (id & 127) >> 4;
    const int cx = id & 15;
    const float* S = n2 + (size_t)b * 512 * 1024;
    f16* Dn = n2f + (size_t)b * 512 * 1024;
    f16* Dt = n2t + (size_t)b * 1024 * 512;
    __shared__ f16 Ts[64 * 72];
    const int r0 = ry * 64, c0 = cx * 64;
    const int rr = tid >> 3, cc8 = (tid & 7) * 8;
#pragma unroll
    for (int h = 0; h < 2; ++h) {
        const int row = r0 + rr + 32 * h;
        const float* s = S + (size_t)row * 1024 + c0 + cc8;
        f32x4 a = *(const f32x4*)s, bq = *(const f32x4*)(s + 4);
        f16x8 o;
        o[0] = (f16)a[0]; o[1] = (f16)a[1]; o[2] = (f16)a[2]; o[3] = (f16)a[3];
        o[4] = (f16)bq[0]; o[5] = (f16)bq[1]; o[6] = (f16)bq[2]; o[7] = (f16)bq[3];
        *(f16x8*)&Ts[(rr + 32 * h) * 72 + cc8] = o;
        *(f16x8*)(Dn + (size_t)row * 1024 + c0 + cc8) = o;
    }
    __syncthreads();
    const int j = tid >> 2, k16 = (tid & 3) * 16;
    f16* d = Dt + (size_t)(c0 + j) * 512 + r0 + k16;
    f16x8 o0, o1;
#pragma unroll
    for (int i = 0; i < 8; ++i) {
        o0[i] = Ts[(k16 + i) * 72 + j];
        o1[i] = Ts[(k16 + 8 + i) * 72 + j];
    }
    *(f16x8*)d = o0;
    *(f16x8*)(d + 8) = o1;
}

// ---------------------------------------------------------------------------
// stats_combine: per (b,o) fold 16 partials (log2 domain) ->
//   Sc[b][o] = log2(sum_h e^{E[o][h]}).
__global__ __launch_bounds__(256) void stats_combine(const float* __restrict__ Pm,
                                                     const float* __restrict__ Ps,
                                                     float* __restrict__ Sc) {
    const int g = blockIdx.x * 256 + threadIdx.x;  // 16 * 1024
    const int b = g >> 10, o = g & 1023;
    const int mt = o >> 7, ml = o & 127;
    const float* pm = Pm + ((size_t)(b * 8 + mt) * 16) * 128 + ml;
    const float* ps = Ps + ((size_t)(b * 8 + mt) * 16) * 128 + ml;
    float M = -3.0e38f;
#pragma unroll
    for (int p = 0; p < 16; ++p) M = fmaxf(M, pm[p * 128]);
    float S = 0.f;
#pragma unroll
    for (int p = 0; p < 16; ++p) S += ps[p * 128] * exp2f(pm[p * 128] - M);
    Sc[g] = M + __log2f(S);
}

// ---------------------------------------------------------------------------
// exp-scale of a staged B vector: At = exp2(Et*log2e - Sc)
__device__ __forceinline__ f16x8 expb(f16x8 b, f32x4 cl, f32x4 ch) {
    f16x8 t;
#pragma unroll
    for (int i = 0; i < 4; ++i) t[i] = (f16)exp2f(fmaf((float)b[i], L2E, -cl[i]));
#pragma unroll
    for (int i = 0; i < 4; ++i) t[4 + i] = (f16)exp2f(fmaf((float)b[4 + i], L2E, -ch[i]));
    return t;
}

// ---------------------------------------------------------------------------
// K-loop core. BM=BN=128, BK=32, 256 threads, 4 waves (2m x 2n), wave tile
// 64x64: fa[4] x fb[4] -> 16 MFMA per 8 ds_read_b128.
// LDS: A0 @0 (8K), A1 @8192, B0 @16384, B1 @24576. Row = 64 B.
// Swizzle: 16B slot s of row r lives at s ^ ((r>>1)&3); applied on both
// stage-write (sOff0/1) and fragment-read (swz16).
// Depth-2 global->reg prefetch: set n lives in regs of parity n&1; at step kb
// we ds_write set kb+1 and reload those regs with set kb+3.
// Per thread per step: 2 A slots + 2 B slots (16 B each).
template <int NS, bool EXPB>
__device__ __forceinline__ void gemm_core128(const char* gA, const char* gB,
                                             const float* gS, char* SM,
                                             int sOff0, int sOff1,
                                             int wm, int wn, int col, int swz16,
                                             f32x4 (&acc)[4][4]) {
    f32x4 c0a, c0b, c0c, c0d, c1a, c1b, c1c, c1d;
    // set 0 -> LDS buf0
    f16x8 pa0 = *(const f16x8*)gA, pa1 = *(const f16x8*)(gA + 16);
    f16x8 pb0 = *(const f16x8*)gB, pb1 = *(const f16x8*)(gB + 16);
    if (EXPB) {
        c0a = *(const f32x4*)gS;        c0b = *(const f32x4*)(gS + 4);
        c0c = *(const f32x4*)(gS + 8);  c0d = *(const f32x4*)(gS + 12);
    }
    *(f16x8*)(SM + sOff0) = pa0;
    *(f16x8*)(SM + sOff1) = pa1;
    *(f16x8*)(SM + 16384 + sOff0) = EXPB ? expb(pb0, c0a, c0b) : pb0;
    *(f16x8*)(SM + 16384 + sOff1) = EXPB ? expb(pb1, c0c, c0d) : pb1;
    // set 1 -> parity-1 regs
    f16x8 qa0 = *(const f16x8*)(gA + 64), qa1 = *(const f16x8*)(gA + 80);
    f16x8 qb0 = *(const f16x8*)(gB + 64), qb1 = *(const f16x8*)(gB + 80);
    if (EXPB) {
        c1a = *(const f32x4*)(gS + 32); c1b = *(const f32x4*)(gS + 36);
        c1c = *(const f32x4*)(gS + 40); c1d = *(const f32x4*)(gS + 44);
    }
    // set 2 -> parity-0 regs
    pa0 = *(const f16x8*)(gA + 128); pa1 = *(const f16x8*)(gA + 144);
    pb0 = *(const f16x8*)(gB + 128); pb1 = *(const f16x8*)(gB + 144);
    if (EXPB) {
        c0a = *(const f32x4*)(gS + 64); c0b = *(const f32x4*)(gS + 68);
        c0c = *(const f32x4*)(gS + 72); c0d = *(const f32x4*)(gS + 76);
    }
    WG_BARRIER();
#pragma unroll
    for (int kb = 0; kb < NS; ++kb) {
        const char* Ac = SM + (kb & 1) * 8192;
        const char* Bc = SM + 16384 + (kb & 1) * 8192;
        f16x8 fa[4], fb[4];
#pragma unroll
        for (int u = 0; u < 4; ++u)
            fa[u] = *(const f16x8*)(Ac + (wm + u * 16 + col) * 64 + swz16);
#pragma unroll
        for (int v = 0; v < 4; ++v)
            fb[v] = *(const f16x8*)(Bc + (wn + v * 16 + col) * 64 + swz16);
#pragma unroll
        for (int u = 0; u < 4; ++u)
#pragma unroll
            for (int v = 0; v < 4; ++v)
                acc[u][v] = __builtin_amdgcn_mfma_f32_16x16x32_f16(fa[u], fb[v],
                                                                   acc[u][v], 0, 0, 0);
        if (kb + 1 < NS) {
            char* dA = SM + ((kb + 1) & 1) * 8192;
            char* dB = SM + 16384 + ((kb + 1) & 1) * 8192;
            if ((kb & 1) == 0) {
                *(f16x8*)(dA + sOff0) = qa0;
                *(f16x8*)(dA + sOff1) = qa1;
                *(f16x8*)(dB + sOff0) = EXPB ? expb(qb0, c1a, c1b) : qb0;
                *(f16x8*)(dB + sOff1) = EXPB ? expb(qb1, c1c, c1d) : qb1;
                if (kb + 3 < NS) {
                    qa0 = *(const f16x8*)(gA + (size_t)(kb + 3) * 64);
                    qa1 = *(const f16x8*)(gA + (size_t)(kb + 3) * 64 + 16);
                    qb0 = *(const f16x8*)(gB + (size_t)(kb + 3) * 64);
                    qb1 = *(const f16x8*)(gB + (size_t)(kb + 3) * 64 + 16);
                    if (EXPB) {
                        c1a = *(const f32x4*)(gS + (size_t)(kb + 3) * 32);
                        c1b = *(const f32x4*)(gS + (size_t)(kb + 3) * 32 + 4);
                        c1c = *(const f32x4*)(gS + (size_t)(kb + 3) * 32 + 8);
                        c1d = *(const f32x4*)(gS + (size_t)(kb + 3) * 32 + 12);
                    }
                }
            } else {
                *(f16x8*)(dA + sOff0) = pa0;
                *(f16x8*)(dA + sOff1) = pa1;
                *(f16x8*)(dB + sOff0) = EXPB ? expb(pb0, c0a, c0b) : pb0;
                *(f16x8*)(dB + sOff1) = EXPB ? expb(pb1, c0c, c0d) : pb1;
                if (kb + 3 < NS) {
                    pa0 = *(const f16x8*)(gA + (size_t)(kb + 3) * 64);
                    pa1 = *(const f16x8*)(gA + (size_t)(kb + 3) * 64 + 16);
                    pb0 = *(const f16x8*)(gB + (size_t)(kb + 3) * 64);
                    pb1 = *(const f16x8*)(gB + (size_t)(kb + 3) * 64 + 16);
                    if (EXPB) {
                        c0a = *(const f32x4*)(gS + (size_t)(kb + 3) * 32);
                        c0b = *(const f32x4*)(gS + (size_t)(kb + 3) * 32 + 4);
                        c0c = *(const f32x4*)(gS + (size_t)(kb + 3) * 32 + 8);
                        c0d = *(const f32x4*)(gS + (size_t)(kb + 3) * 32 + 12);
                    }
                }
            }
            WG_BARRIER();
        }
    }
}

// Transposed f16 epilogue: single pass through Tt[128][136]; each wave writes
// its 64x64 quadrant, then 256 threads copy 128 coalesced rows of 128.
__device__ __forceinline__ void epilogue_tr128(f32x4 (&acc)[4][4], char* SM,
                                               f16* dst0, int dstRow, int m0,
                                               int n0, int tid) {
    const int lane = tid & 63, wave = tid >> 6;
    const int col = lane & 15, quad = lane >> 4;
    const int wm = ((wave >> 1) & 1) * 64, wn = (wave & 1) * 64;
    WG_BARRIER();  // all frag reads of SM done before overwrite
    f16* Tt = (f16*)SM;
#pragma unroll
    for (int u = 0; u < 4; ++u)
#pragma unroll
        for (int v = 0; v < 4; ++v) {
            f16x4 p;
#pragma unroll
            for (int r = 0; r < 4; ++r) p[r] = (f16)acc[u][v][r];
            *(f16x4*)&Tt[(wn + v * 16 + col) * 136 + wm + u * 16 + quad * 4] = p;
        }
    WG_BARRIER();
    const int j = tid >> 1, seg = (tid & 1) * 64;
    f16* dst = dst0 + (size_t)(n0 + j) * dstRow + m0 + seg;
#pragma unroll
    for (int c8 = 0; c8 < 64; c8 += 8)
        *(f16x8*)(dst + c8) = *(const f16x8*)&Tt[j * 136 + seg + c8];
}

// ---------------------------------------------------------------------------
// GEMM1: Xt[b][o][c] = (n1f[b] @ Wf^T)^T.  M=512, N=1024, K=1024. 512 blocks.
__global__ __launch_bounds__(256) void gemm1_nt_xt(const f16* __restrict__ A,
                                                   const f16* __restrict__ Bw,
                                                   f16* __restrict__ Xt) {
    const int K = 1024;
    const int id = blockIdx.x;
    const int xcd = id & 7, loc = id >> 3;         // loc 0..63
    const int b = xcd * 2 + (loc >> 5);
    const int m0 = ((loc >> 3) & 3) * 128;
    const int n0 = (loc & 7) * 128;
    A += (size_t)b * 512 * K;
    Xt += (size_t)b * 1024 * 512;
    __shared__ __attribute__((aligned(16))) char SM[34816];
    const int tid = threadIdx.x, lane = tid & 63, wave = tid >> 6;
    const int col = lane & 15, quad = lane >> 4;
    const int wm = ((wave >> 1) & 1) * 64, wn = (wave & 1) * 64;
    const int srow = tid >> 1, spair = (tid & 1) * 2;
    const int sx = (srow >> 1) & 3;
    const int sOff0 = srow * 64 + ((spair ^ sx) * 16);
    const int sOff1 = srow * 64 + (((spair + 1) ^ sx) * 16);
    const int swz16 = (quad ^ ((col >> 1) & 3)) * 16;
    const char* gA = (const char*)A + (size_t)(m0 + srow) * K * 2 + spair * 16;
    const char* gB = (const char*)Bw + (size_t)(n0 + srow) * K * 2 + spair * 16;
    f32x4 acc[4][4] = {};
    gemm_core128<32, false>(gA, gB, nullptr, SM, sOff0, sOff1, wm, wn, col, swz16, acc);
    epilogue_tr128(acc, SM, Xt, 512, m0, n0, tid);
}

// ---------------------------------------------------------------------------
// GEMM2: Et[b][h][o] (f16) = (Xt[b] @ n2t[b]^T)^T.  M=1024, N=1024, K=512.
// 1024 blocks. Epilogue also emits per-block column (per-o) softmax partials
// computed from the f16-ROUNDED acc values (bit-consistent with stored Et).
__global__ __launch_bounds__(256) void gemm2_nt_et(const f16* __restrict__ A,
                                                   const f16* __restrict__ B,
                                                   f16* __restrict__ Et,
                                                   float* __restrict__ Pm,
                                                   float* __restrict__ Ps) {
    const int K = 512;
    const int id = blockIdx.x;
    const int xcd = id & 7, loc = id >> 3;         // loc 0..127
    const int b = xcd * 2 + (loc >> 6);
    const int m0 = ((loc >> 3) & 7) * 128;
    const int n0 = (loc & 7) * 128;
    A += (size_t)b * 1024 * K;
    B += (size_t)b * 1024 * K;
    Et += (size_t)b * 1024 * 1024;
    __shared__ __attribute__((aligned(16))) char SM[34816];
    const int tid = threadIdx.x, lane = tid & 63, wave = tid >> 6;
    const int col = lane & 15, quad = lane >> 4;
    const int wm = ((wave >> 1) & 1) * 64, wn = (wave & 1) * 64;
    const int srow = tid >> 1, spair = (tid & 1) * 2;
    const int sx = (srow >> 1) & 3;
    const int sOff0 = srow * 64 + ((spair ^ sx) * 16);
    const int sOff1 = srow * 64 + (((spair + 1) ^ sx) * 16);
    const int swz16 = (quad ^ ((col >> 1) & 3)) * 16;
    const char* gA = (const char*)A + (size_t)(m0 + srow) * K * 2 + spair * 16;
    const char* gB = (const char*)B + (size_t)(n0 + srow) * K * 2 + spair * 16;
    f32x4 acc[4][4] = {};
    gemm_core128<16, false>(gA, gB, nullptr, SM, sOff0, sOff1, wm, wn, col, swz16, acc);

    // ---- fused column-softmax partials (log2 domain), registers + shfl only.
    // Values are f16-rounded FIRST so stats match the Et that gemm3 re-reads.
    // Thread value (u,v,r): m = wm+u*16+quad*4+r (o), n = wn+v*16+col (h).
    {
        float pm[16], ps[16];
#pragma unroll
        for (int u = 0; u < 4; ++u)
#pragma unroll
            for (int r = 0; r < 4; ++r) {
                float w0 = (float)(f16)acc[u][0][r] * L2E;
                float w1 = (float)(f16)acc[u][1][r] * L2E;
                float w2 = (float)(f16)acc[u][2][r] * L2E;
                float w3 = (float)(f16)acc[u][3][r] * L2E;
                float m2 = fmaxf(fmaxf(w0, w1), fmaxf(w2, w3));
                float s = exp2f(w0 - m2) + exp2f(w1 - m2) +
                          exp2f(w2 - m2) + exp2f(w3 - m2);
                pm[u * 4 + r] = m2;
                ps[u * 4 + r] = s;
            }
#pragma unroll
        for (int d = 1; d < 16; d <<= 1)
#pragma unroll
            for (int i = 0; i < 16; ++i) {
                float om = __shfl_xor(pm[i], d, 64);
                float os = __shfl_xor(ps[i], d, 64);
                float nm = fmaxf(pm[i], om);
                ps[i] = ps[i] * exp2f(pm[i] - nm) + os * exp2f(om - nm);
                pm[i] = nm;
            }
        if (col == 0) {
            const int part = ((b * 8 + (m0 >> 7)) * 8 + (n0 >> 7)) * 2 + (wave & 1);
            float* bm = Pm + (size_t)part * 128;
            float* bs = Ps + (size_t)part * 128;
#pragma unroll
            for (int i = 0; i < 16; ++i) {
                const int ml = wm + (i >> 2) * 16 + quad * 4 + (i & 3);
                bm[ml] = pm[i];
                bs[ml] = ps[i];
            }
        }
    }

    epilogue_tr128(acc, SM, Et, 1024, m0, n0, tid);
}

// ---------------------------------------------------------------------------
// GEMM3: out[b][c][j] (f32) = n2f[b](f16) @ At[b]^T, At[j][o] =
// exp2(Et[j][o]*log2e - Sc[b][o]) applied at B-staging (depth-2 covered).
// M=512, N=1024, K=1024. 512 blocks.
__global__ __launch_bounds__(256) void gemm3_nt_out(const f16* __restrict__ A,
                                                    const f16* __restrict__ Et,
                                                    const float* __restrict__ Sc,
                                                    float* __restrict__ C) {
    const int K = 1024;
    const int id = blockIdx.x;
    const int xcd = id & 7, loc = id >> 3;         // loc 0..63
    const int b = xcd * 2 + (loc >> 5);
    const int m0 = ((loc >> 3) & 3) * 128;
    const int n0 = (loc & 7) * 128;
    A += (size_t)b * 512 * K;
    Et += (size_t)b * 1024 * K;
    Sc += (size_t)b * 1024;
    C += (size_t)b * 512 * 1024;
    __shared__ __attribute__((aligned(16))) char SM[34816];
    const int tid = threadIdx.x, lane = tid & 63, wave = tid >> 6;
    const int col = lane & 15, quad = lane >> 4;
    const int wm = ((wave >> 1) & 1) * 64, wn = (wave & 1) * 64;
    const int srow = tid >> 1, spair = (tid & 1) * 2;
    const int sx = (srow >> 1) & 3;
    const int sOff0 = srow * 64 + ((spair ^ sx) * 16);
    const int sOff1 = srow * 64 + (((spair + 1) ^ sx) * 16);
    const int swz16 = (quad ^ ((col >> 1) & 3)) * 16;
    const char* gA = (const char*)A + (size_t)(m0 + srow) * K * 2 + spair * 16;
    const char* gB = (const char*)Et + (size_t)(n0 + srow) * K * 2 + spair * 16;
    const float* gS = Sc + spair * 8;  // o-base of this thread's staged elems
    f32x4 acc[4][4] = {};
    gemm_core128<32, true>(gA, gB, gS, SM, sOff0, sOff1, wm, wn, col, swz16, acc);

#pragma unroll
    for (int u = 0; u < 4; ++u)
#pragma unroll
        for (int v = 0; v < 4; ++v)
#pragma unroll
            for (int r = 0; r < 4; ++r)
                C[(size_t)(m0 + wm + u * 16 + quad * 4 + r) * 1024 + n0 + wn + v * 16 + col] =
                    acc[u][v][r];
}

// ---------------------------------------------------------------------------
extern "C" void kernel_launch(void* const* d_in, const int* in_sizes, int n_in,
                              void* d_out, int out_size, void* d_ws, size_t ws_size,
                              hipStream_t stream) {
    const float* n1 = (const float*)d_in[0];
    const float* n2 = (const float*)d_in[1];
    const float* Wc = (const float*)d_in[2];
    float* out = (float*)d_out;
    char* ws = (char*)d_ws;

    f16* n2t = (f16*)(ws);                   // [0,16M)   prep -> gemm2
    f16* Xt  = (f16*)(ws + (16u << 20));     // [16,32M)  gemm1 -> gemm2
    f16* Wf  = (f16*)(ws + (32u << 20));     // [32,34M)  prep -> gemm1 (dead before Et)
    f16* Et  = (f16*)(ws + (32u << 20));     // [32,64M)  gemm2 -> gemm3
    f16* n1f = (f16*)(ws + (64u << 20));     // [64,80M)  prep -> gemm1 (dead after)
    f16* n2f = (f16*)(ws + (80u << 20));     // [80,96M)  prep -> gemm3
    float* Pm = (float*)(ws + (64u << 20));            // 1 MiB, over dead n1f
    float* Ps = (float*)(ws + (65u << 20));            // 1 MiB
    float* Sc = (float*)(ws + (66u << 20));            // 64 KiB (log2 units)

    prep<<<6656, dim3(256), 0, stream>>>(n1, Wc, n2, n1f, Wf, n2f, n2t);
    gemm1_nt_xt<<<512, dim3(256), 0, stream>>>(n1f, Wf, Xt);
    gemm2_nt_et<<<1024, dim3(256), 0, stream>>>(Xt, n2t, Et, Pm, Ps);
    stats_combine<<<64, dim3(256), 0, stream>>>(Pm, Ps, Sc);
    gemm3_nt_out<<<512, dim3(256), 0, stream>>>(n2f, Et, Sc, out);
}